// Round 3
// baseline (353.374 us; speedup 1.0000x reference)
//
#include <hip/hip_runtime.h>
#include <hip/hip_bf16.h>

#define NN 4096
#define NFEAT 512
#define NHID 64
#define NHEAD 8
#define NCLASS 16
#define CAP 192
#define LALPHA 0.2f

// ---------- helpers ----------
__device__ __forceinline__ float b2f(unsigned short h) {
    return __uint_as_float(((unsigned int)h) << 16);
}
__device__ __forceinline__ float waveMax(float v) {
#pragma unroll
    for (int m = 32; m >= 1; m >>= 1) v = fmaxf(v, __shfl_xor(v, m, 64));
    return v;
}
__device__ __forceinline__ float waveSum(float v) {
#pragma unroll
    for (int m = 32; m >= 1; m >>= 1) v += __shfl_xor(v, m, 64);
    return v;
}

// ---------- detect input dtypes from raw bits ----------
// flags[0]=1 if float inputs are bf16 (else fp32); flags[1]=1 if edge ints are int64
__global__ void k_detect(const unsigned int* __restrict__ fw,
                         const int* __restrict__ ew, int* __restrict__ flags) {
    __shared__ int s_bf, s_i64;
    int t = threadIdx.x;
    if (t == 0) { s_bf = 0; s_i64 = 0; }
    __syncthreads();
    unsigned int w = fw[t];
    unsigned int lo = w & 0xffffu;
    unsigned int e = (lo >> 7) & 0xffu;
    if (lo == 0u || (e >= 100u && e <= 140u)) atomicAdd(&s_bf, 1);
    if (ew[2 * t + 1] == 0) atomicAdd(&s_i64, 1);
    __syncthreads();
    if (t == 0) { flags[0] = (s_bf >= 200); flags[1] = (s_i64 >= 250); }
}

// ---------- convert a float input to fp32 (branch is uniform) ----------
__global__ void k_convert(const void* __restrict__ src, float* __restrict__ dst,
                          int n, const int* __restrict__ flags) {
    int i = blockIdx.x * blockDim.x + threadIdx.x;
    int stride = gridDim.x * blockDim.x;
    if (flags[0]) {
        const unsigned short* p = (const unsigned short*)src;
        for (; i < n; i += stride) dst[i] = b2f(p[i]);
    } else {
        const float* p = (const float*)src;
        for (; i < n; i += stride) dst[i] = p[i];
    }
}

// ---------- zero bits+deg+colmeans ----------
__global__ void k_zero(unsigned int* __restrict__ p, int n) {
    int i = blockIdx.x * blockDim.x + threadIdx.x;
    int stride = gridDim.x * blockDim.x;
    for (; i < n; i += stride) p[i] = 0u;
}

// ---------- dedup edges, build padded CSR ----------
__global__ void k_build_csr(const int* __restrict__ e32, int E,
                            const int* __restrict__ flags,
                            unsigned int* __restrict__ bits,
                            int* __restrict__ deg, int* __restrict__ csr) {
    int i = blockIdx.x * blockDim.x + threadIdx.x;
    if (i >= E) return;
    int s, t;
    if (flags[1]) { s = e32[2 * i]; t = e32[2 * (E + i)]; }
    else          { s = e32[i];     t = e32[E + i]; }
    s &= (NN - 1); t &= (NN - 1);   // safety: finite-wrong beats OOB
    unsigned int pos = (unsigned int)s * NN + (unsigned int)t;
    unsigned int mask = 1u << (pos & 31u);
    unsigned int old = atomicOr(&bits[pos >> 5], mask);
    if (!(old & mask)) {
        int j = atomicAdd(&deg[s], 1);
        if (j < CAP) csr[s * CAP + j] = t;
    }
}

// ---------- H1[h] = features @ W_heads[h] (fp32) ----------
__global__ void __launch_bounds__(256)
k_gemm1(const float* __restrict__ A,   // [NN][NFEAT]
        const float* __restrict__ W,   // [NHEAD][NFEAT][NHID]
        float* __restrict__ H) {       // [NHEAD][NN][NHID]
    __shared__ float Ast[16][68];
    __shared__ float Bs[16][64];
    int t = threadIdx.x;
    int h = blockIdx.y;
    int m0 = blockIdx.x * 64;
    int tx = t & 15, ty = t >> 4;
    float acc[4][4] = {};
    const float* Wh = W + (size_t)h * NFEAT * NHID;
    int ar = t >> 2, ak = (t & 3) * 4;
    int bk = t >> 4, bc = (t & 15) * 4;

    for (int k0 = 0; k0 < NFEAT; k0 += 16) {
        float4 av = *(const float4*)&A[(size_t)(m0 + ar) * NFEAT + k0 + ak];
        float4 bv = *(const float4*)&Wh[(size_t)(k0 + bk) * NHID + bc];
        Ast[ak + 0][ar] = av.x;
        Ast[ak + 1][ar] = av.y;
        Ast[ak + 2][ar] = av.z;
        Ast[ak + 3][ar] = av.w;
        *(float4*)&Bs[bk][bc] = bv;
        __syncthreads();
#pragma unroll
        for (int kk = 0; kk < 16; ++kk) {
            float4 a4 = *(const float4*)&Ast[kk][ty * 4];
            float4 b4 = *(const float4*)&Bs[kk][tx * 4];
            float aa[4] = {a4.x, a4.y, a4.z, a4.w};
            float bb[4] = {b4.x, b4.y, b4.z, b4.w};
#pragma unroll
            for (int i = 0; i < 4; ++i)
#pragma unroll
                for (int j = 0; j < 4; ++j) acc[i][j] += aa[i] * bb[j];
        }
        __syncthreads();
    }
#pragma unroll
    for (int i = 0; i < 4; ++i) {
        float4 o = make_float4(acc[i][0], acc[i][1], acc[i][2], acc[i][3]);
        *(float4*)&H[((size_t)h * NN + m0 + ty * 4 + i) * NHID + tx * 4] = o;
    }
}

// ---------- per-(node,head) score halves ----------
__global__ void k_scores1(const float* __restrict__ H, const float* __restrict__ a_heads,
                          float* __restrict__ s1, float* __restrict__ s2) {
    int idx = blockIdx.x * 4 + (threadIdx.x >> 6);
    int lane = threadIdx.x & 63;
    int n = idx & (NN - 1), h = idx >> 12;
    float v = H[((size_t)h * NN + n) * NHID + lane];
    float a1 = a_heads[h * 2 * NHID + lane];
    float a2 = a_heads[h * 2 * NHID + NHID + lane];
    float r1 = waveSum(v * a1);
    float r2 = waveSum(v * a2);
    if (lane == 0) { s1[idx] = r1; s2[idx] = r2; }
}

// ---------- column sums of H1 (deg==0 fallback) ----------
__global__ void k_colmean1(const float* __restrict__ H, float* __restrict__ cm1) {
    int h = blockIdx.y, lane = threadIdx.x;
    int r0 = blockIdx.x * 128;
    float acc = 0.f;
    for (int r = 0; r < 128; ++r) acc += H[((size_t)h * NN + r0 + r) * NHID + lane];
    atomicAdd(&cm1[h * NHID + lane], acc);
}

// ---------- layer-1 edge softmax + SpMM + bias + ELU + concat ----------
__global__ void k_attn1(const int* __restrict__ deg, const int* __restrict__ csr,
                        const float* __restrict__ s1, const float* __restrict__ s2,
                        const float* __restrict__ H, const float* __restrict__ b_heads,
                        const float* __restrict__ cm1, float* __restrict__ X) {
    int idx = blockIdx.x * 4 + (threadIdx.x >> 6);
    int lane = threadIdx.x & 63;
    int n = idx & (NN - 1), h = idx >> 12;
    int d = deg[n]; if (d > CAP) d = CAP;
    float out;
    if (d == 0) {
        out = cm1[h * NHID + lane] * (1.0f / NN);
    } else {
        float s1n = s1[idx];
        const float* s2h = s2 + (size_t)h * NN;
        const int* row = csr + (size_t)n * CAP;
        float m = -INFINITY;
        for (int j = lane; j < d; j += 64) {
            float e = s1n + s2h[row[j]];
            e = e >= 0.f ? e : LALPHA * e;
            m = fmaxf(m, e);
        }
        m = waveMax(m);
        float den = 0.f;
        for (int j = lane; j < d; j += 64) {
            float e = s1n + s2h[row[j]];
            e = e >= 0.f ? e : LALPHA * e;
            den += __expf(e - m);
        }
        den = waveSum(den);
        const float* Hh = H + (size_t)h * NN * NHID;
        float acc = 0.f;
        for (int j = 0; j < d; ++j) {
            int tt = row[j];
            float e = s1n + s2h[tt];
            e = e >= 0.f ? e : LALPHA * e;
            acc += __expf(e - m) * Hh[(size_t)tt * NHID + lane];
        }
        out = acc / den;
    }
    out += b_heads[h * NHID + lane];
    out = out > 0.f ? out : __expf(out) - 1.f;     // ELU
    X[(size_t)n * NFEAT + h * NHID + lane] = out;
}

// ---------- out2 = X @ W_out ----------
__global__ void k_gemm2(const float* __restrict__ X, const float* __restrict__ Wo,
                        float* __restrict__ out2) {
    int gid = blockIdx.x * blockDim.x + threadIdx.x;
    int n = gid >> 4, c = gid & 15;
    const float* xr = X + (size_t)n * NFEAT;
    float acc = 0.f;
#pragma unroll 4
    for (int k = 0; k < NFEAT; ++k) acc += xr[k] * Wo[k * NCLASS + c];
    out2[n * NCLASS + c] = acc;
}

// ---------- layer-2 score halves ----------
__global__ void k_scores2(const float* __restrict__ out2, const float* __restrict__ a_out,
                          float* __restrict__ s1o, float* __restrict__ s2o) {
    int n = blockIdx.x * blockDim.x + threadIdx.x;
    if (n >= NN) return;
    float r1 = 0.f, r2 = 0.f;
#pragma unroll
    for (int c = 0; c < NCLASS; ++c) {
        float v = out2[n * NCLASS + c];
        r1 += v * a_out[c];
        r2 += v * a_out[NCLASS + c];
    }
    s1o[n] = r1; s2o[n] = r2;
}

// ---------- column sums of out2 (deg==0 fallback) ----------
__global__ void k_colmean2(const float* __restrict__ out2, float* __restrict__ cm2) {
    int tid = threadIdx.x;
    int c = tid & 15;
    int base = blockIdx.x * 256 + (tid >> 4);
    float acc = 0.f;
    for (int p = 0; p < 16; ++p) acc += out2[(base + p * 16) * NCLASS + c];
    atomicAdd(&cm2[c], acc);
}

// ---------- layer-2 softmax + SpMM + bias + log_softmax (fp32 output) ----------
__global__ void k_attn2(const int* __restrict__ deg, const int* __restrict__ csr,
                        const float* __restrict__ s1o, const float* __restrict__ s2o,
                        const float* __restrict__ out2, const float* __restrict__ b_out,
                        const float* __restrict__ cm2, float* __restrict__ outp) {
    int n = blockIdx.x * 4 + (threadIdx.x >> 6);
    int lane = threadIdx.x & 63;
    int c = lane & 15;
    int d = deg[n]; if (d > CAP) d = CAP;
    float val;
    if (d == 0) {
        val = cm2[c] * (1.0f / NN);
    } else {
        float s1n = s1o[n];
        const int* row = csr + (size_t)n * CAP;
        float m = -INFINITY;
        for (int j = lane; j < d; j += 64) {
            float e = s1n + s2o[row[j]];
            e = e >= 0.f ? e : LALPHA * e;
            m = fmaxf(m, e);
        }
        m = waveMax(m);
        float den = 0.f;
        for (int j = lane; j < d; j += 64) {
            float e = s1n + s2o[row[j]];
            e = e >= 0.f ? e : LALPHA * e;
            den += __expf(e - m);
        }
        den = waveSum(den);
        int g = lane >> 4;
        float acc = 0.f;
        for (int j = g; j < d; j += 4) {
            int tt = row[j];
            float e = s1n + s2o[tt];
            e = e >= 0.f ? e : LALPHA * e;
            acc += __expf(e - m) * out2[tt * NCLASS + c];
        }
        acc += __shfl_xor(acc, 16, 64);
        acc += __shfl_xor(acc, 32, 64);
        val = acc / den;
    }
    val += b_out[c];
    float mx = val;
#pragma unroll
    for (int msk = 8; msk >= 1; msk >>= 1) mx = fmaxf(mx, __shfl_xor(mx, msk, 16));
    float se = __expf(val - mx);
#pragma unroll
    for (int msk = 8; msk >= 1; msk >>= 1) se += __shfl_xor(se, msk, 16);
    float res = val - mx - __logf(se);
    if (lane < 16) outp[n * NCLASS + lane] = res;   // fp32 output
}

extern "C" void kernel_launch(void* const* d_in, const int* in_sizes, int n_in,
                              void* d_out, int out_size, void* d_ws, size_t ws_size,
                              hipStream_t stream) {
    const void* features = d_in[0];
    const int*  edges    = (const int*)d_in[1];
    const void* W_heads  = d_in[2];
    const void* a_heads  = d_in[3];
    const void* b_heads  = d_in[4];
    const void* W_out    = d_in[5];
    const void* a_out    = d_in[6];
    const void* b_out    = d_in[7];
    int E = in_sizes[1] / 2;

    // ---- workspace layout (all fp32/int32, 4B units) ----
    int* flags = (int*)d_ws;                                   // 64 (header)
    unsigned int* bits = (unsigned int*)(flags + 64);          // NN*NN/32
    int*   deg  = (int*)(bits + (NN * NN / 32));               // NN
    float* cm1  = (float*)(deg + NN);                          // NHEAD*NHID
    float* cm2  = cm1 + NHEAD * NHID;                          // NCLASS
    int*   csr  = (int*)(cm2 + NCLASS);                        // NN*CAP
    float* H1   = (float*)(csr + NN * CAP);                    // NHEAD*NN*NHID
    float* s1   = H1 + (size_t)NHEAD * NN * NHID;              // NHEAD*NN
    float* s2   = s1 + NHEAD * NN;                             // NHEAD*NN
    float* X    = s2 + NHEAD * NN;                             // NN*NFEAT
    float* out2 = X + (size_t)NN * NFEAT;                      // NN*NCLASS
    float* s1o  = out2 + NN * NCLASS;                          // NN
    float* s2o  = s1o + NN;                                    // NN
    float* featf = s2o + NN;                                   // NN*NFEAT
    float* Whf   = featf + (size_t)NN * NFEAT;                 // NHEAD*NFEAT*NHID
    float* ahf   = Whf + NHEAD * NFEAT * NHID;                 // NHEAD*2*NHID
    float* bhf   = ahf + NHEAD * 2 * NHID;                     // NHEAD*NHID
    float* Wof   = bhf + NHEAD * NHID;                         // NFEAT*NCLASS
    float* aof   = Wof + NFEAT * NCLASS;                       // 2*NCLASS
    float* bof   = aof + 2 * NCLASS;                           // NCLASS
    float* outp  = (float*)d_out;

    hipLaunchKernelGGL(k_detect, dim3(1), dim3(256), 0, stream,
                       (const unsigned int*)features, edges, flags);
    hipLaunchKernelGGL(k_convert, dim3(2048), dim3(256), 0, stream, features, featf, NN * NFEAT, flags);
    hipLaunchKernelGGL(k_convert, dim3(512), dim3(256), 0, stream, W_heads, Whf, NHEAD * NFEAT * NHID, flags);
    hipLaunchKernelGGL(k_convert, dim3(4), dim3(256), 0, stream, a_heads, ahf, NHEAD * 2 * NHID, flags);
    hipLaunchKernelGGL(k_convert, dim3(2), dim3(256), 0, stream, b_heads, bhf, NHEAD * NHID, flags);
    hipLaunchKernelGGL(k_convert, dim3(32), dim3(256), 0, stream, W_out, Wof, NFEAT * NCLASS, flags);
    hipLaunchKernelGGL(k_convert, dim3(1), dim3(64), 0, stream, a_out, aof, 2 * NCLASS, flags);
    hipLaunchKernelGGL(k_convert, dim3(1), dim3(64), 0, stream, b_out, bof, NCLASS, flags);

    int zcount = NN * NN / 32 + NN + NHEAD * NHID + NCLASS;
    hipLaunchKernelGGL(k_zero, dim3(1024), dim3(256), 0, stream, bits, zcount);
    hipLaunchKernelGGL(k_build_csr, dim3((E + 255) / 256), dim3(256), 0, stream,
                       edges, E, flags, bits, deg, csr);
    hipLaunchKernelGGL(k_gemm1, dim3(NN / 64, NHEAD), dim3(256), 0, stream, featf, Whf, H1);
    hipLaunchKernelGGL(k_scores1, dim3(NN * NHEAD / 4), dim3(256), 0, stream, H1, ahf, s1, s2);
    hipLaunchKernelGGL(k_colmean1, dim3(32, NHEAD), dim3(64), 0, stream, H1, cm1);
    hipLaunchKernelGGL(k_attn1, dim3(NN * NHEAD / 4), dim3(256), 0, stream,
                       deg, csr, s1, s2, H1, bhf, cm1, X);
    hipLaunchKernelGGL(k_gemm2, dim3(NN * NCLASS / 256), dim3(256), 0, stream, X, Wof, out2);
    hipLaunchKernelGGL(k_scores2, dim3(NN / 256), dim3(256), 0, stream, out2, aof, s1o, s2o);
    hipLaunchKernelGGL(k_colmean2, dim3(16), dim3(256), 0, stream, out2, cm2);
    hipLaunchKernelGGL(k_attn2, dim3(NN / 4), dim3(256), 0, stream,
                       deg, csr, s1o, s2o, out2, bof, cm2, outp);
}

// Round 4
// 214.709 us; speedup vs baseline: 1.6458x; 1.6458x over previous
//
#include <hip/hip_runtime.h>
#include <hip/hip_bf16.h>

#define NN 4096
#define NFEAT 512
#define NHID 64
#define NHEAD 8
#define NCLASS 16
#define CAP 192
#define LALPHA 0.2f

#define SZ0 (NN*NFEAT)
#define SZ1 (NHEAD*NFEAT*NHID)
#define SZ2 (NHEAD*2*NHID)
#define SZ3 (NHEAD*NHID)
#define SZ4 (NFEAT*NCLASS)
#define SZ5 (2*NCLASS)
#define SZ6 (NCLASS)

// ---------- helpers ----------
__device__ __forceinline__ float b2f(unsigned short h) {
    return __uint_as_float(((unsigned int)h) << 16);
}
__device__ __forceinline__ float waveMax(float v) {
#pragma unroll
    for (int m = 32; m >= 1; m >>= 1) v = fmaxf(v, __shfl_xor(v, m, 64));
    return v;
}
__device__ __forceinline__ float waveSum(float v) {
#pragma unroll
    for (int m = 32; m >= 1; m >>= 1) v += __shfl_xor(v, m, 64);
    return v;
}
__device__ __forceinline__ float lrelu(float e) {
    return e >= 0.f ? e : LALPHA * e;
}

// ---------- zero bits+deg+cm1+cm2 ----------
__global__ void k_zero(unsigned int* __restrict__ p, int n) {
    int i = blockIdx.x * blockDim.x + threadIdx.x;
    int stride = gridDim.x * blockDim.x;
    for (; i < n; i += stride) p[i] = 0u;
}

// ---------- convert all float inputs to fp32, contiguous dst ----------
// inline per-block bf16 detection (wave-0 ballot over first 64 words of features)
__global__ void k_convert_all(const void* __restrict__ s0, const void* __restrict__ s1_,
                              const void* __restrict__ s2_, const void* __restrict__ s3_,
                              const void* __restrict__ s4_, const void* __restrict__ s5_,
                              const void* __restrict__ s6_, float* __restrict__ dst) {
    __shared__ int sbf;
    int t = threadIdx.x;
    if (t < 64) {
        unsigned int w = ((const unsigned int*)s0)[t];
        unsigned int lo = w & 0xffffu, e = (lo >> 7) & 0xffu;
        unsigned long long bal = __ballot(lo == 0u || (e >= 100u && e <= 140u));
        if (t == 0) sbf = (__popcll(bal) >= 40);
    }
    __syncthreads();
    bool bf = (sbf != 0);
    const int O1 = SZ0, O2 = O1 + SZ1, O3 = O2 + SZ2, O4 = O3 + SZ3;
    const int O5 = O4 + SZ4, O6 = O5 + SZ5, TOT = O6 + SZ6;
    int i = blockIdx.x * blockDim.x + t;
    int stride = gridDim.x * blockDim.x;
    for (; i < TOT; i += stride) {
        const void* sp; int off;
        if (i < O1)      { sp = s0;  off = i; }
        else if (i < O2) { sp = s1_; off = i - O1; }
        else if (i < O3) { sp = s2_; off = i - O2; }
        else if (i < O4) { sp = s3_; off = i - O3; }
        else if (i < O5) { sp = s4_; off = i - O4; }
        else if (i < O6) { sp = s5_; off = i - O5; }
        else             { sp = s6_; off = i - O6; }
        dst[i] = bf ? b2f(((const unsigned short*)sp)[off]) : ((const float*)sp)[off];
    }
}

// ---------- dedup edges, build padded CSR (inline int64 detection) ----------
__global__ void k_build_csr(const int* __restrict__ e32, int E,
                            unsigned int* __restrict__ bits,
                            int* __restrict__ deg, int* __restrict__ csr) {
    __shared__ int s64f;
    int t = threadIdx.x;
    if (t < 64) {
        unsigned long long bal = __ballot(e32[2 * t + 1] == 0);
        if (t == 0) s64f = (__popcll(bal) >= 48);
    }
    __syncthreads();
    int i = blockIdx.x * blockDim.x + t;
    if (i >= E) return;
    int s, tt;
    if (s64f) { s = e32[2 * i]; tt = e32[2 * (E + i)]; }
    else      { s = e32[i];     tt = e32[E + i]; }
    s &= (NN - 1); tt &= (NN - 1);
    unsigned int pos = (unsigned int)s * NN + (unsigned int)tt;
    unsigned int mask = 1u << (pos & 31u);
    unsigned int old = atomicOr(&bits[pos >> 5], mask);
    if (!(old & mask)) {
        int j = atomicAdd(&deg[s], 1);
        if (j < CAP) csr[s * CAP + j] = tt;
    }
}

// ---------- gemm1 + fused scores1 + colmean1 ----------
__global__ void __launch_bounds__(256)
k_gemm1f(const float* __restrict__ A,    // [NN][NFEAT]
         const float* __restrict__ W,    // [NHEAD][NFEAT][NHID]
         const float* __restrict__ ah,   // [NHEAD][2*NHID]
         float* __restrict__ H,          // [NHEAD][NN][NHID]
         float* __restrict__ s1, float* __restrict__ s2,
         float* __restrict__ cm1) {
    __shared__ float Ast[16][68];
    __shared__ float Bs[16][64];
    __shared__ float cms[64];
    int t = threadIdx.x;
    int h = blockIdx.y;
    int m0 = blockIdx.x * 64;
    int tx = t & 15, ty = t >> 4;
    float acc[4][4] = {};
    const float* Wh = W + (size_t)h * NFEAT * NHID;
    int ar = t >> 2, ak = (t & 3) * 4;
    int bk = t >> 4, bc = (t & 15) * 4;
    if (t < 64) cms[t] = 0.f;

    for (int k0 = 0; k0 < NFEAT; k0 += 16) {
        float4 av = *(const float4*)&A[(size_t)(m0 + ar) * NFEAT + k0 + ak];
        float4 bv = *(const float4*)&Wh[(size_t)(k0 + bk) * NHID + bc];
        Ast[ak + 0][ar] = av.x;
        Ast[ak + 1][ar] = av.y;
        Ast[ak + 2][ar] = av.z;
        Ast[ak + 3][ar] = av.w;
        *(float4*)&Bs[bk][bc] = bv;
        __syncthreads();
#pragma unroll
        for (int kk = 0; kk < 16; ++kk) {
            float4 a4 = *(const float4*)&Ast[kk][ty * 4];
            float4 b4 = *(const float4*)&Bs[kk][tx * 4];
            float aa[4] = {a4.x, a4.y, a4.z, a4.w};
            float bb[4] = {b4.x, b4.y, b4.z, b4.w};
#pragma unroll
            for (int i = 0; i < 4; ++i)
#pragma unroll
                for (int j = 0; j < 4; ++j) acc[i][j] += aa[i] * bb[j];
        }
        __syncthreads();
    }
    // write H tile
#pragma unroll
    for (int i = 0; i < 4; ++i) {
        float4 o = make_float4(acc[i][0], acc[i][1], acc[i][2], acc[i][3]);
        *(float4*)&H[((size_t)h * NN + m0 + ty * 4 + i) * NHID + tx * 4] = o;
    }
    // fused scores: s1/s2 per row via 16-lane shuffle reduction
    const float* a1 = ah + h * 2 * NHID;
    float p1[4] = {}, p2[4] = {};
#pragma unroll
    for (int i = 0; i < 4; ++i)
#pragma unroll
        for (int j = 0; j < 4; ++j) {
            p1[i] += acc[i][j] * a1[tx * 4 + j];
            p2[i] += acc[i][j] * a1[NHID + tx * 4 + j];
        }
#pragma unroll
    for (int m = 8; m >= 1; m >>= 1)
#pragma unroll
        for (int i = 0; i < 4; ++i) {
            p1[i] += __shfl_xor(p1[i], m, 64);
            p2[i] += __shfl_xor(p2[i], m, 64);
        }
    if (tx == 0) {
#pragma unroll
        for (int i = 0; i < 4; ++i) {
            s1[(h << 12) + m0 + ty * 4 + i] = p1[i];
            s2[(h << 12) + m0 + ty * 4 + i] = p2[i];
        }
    }
    // fused colmean partial
#pragma unroll
    for (int j = 0; j < 4; ++j) {
        float cs = acc[0][j] + acc[1][j] + acc[2][j] + acc[3][j];
        atomicAdd(&cms[tx * 4 + j], cs);
    }
    __syncthreads();
    if (t < 64) atomicAdd(&cm1[h * NHID + t], cms[t]);
}

// ---------- layer-1: softmax + SpMM + bias + ELU + concat ----------
// wave per (n,h): weights precomputed into per-wave LDS, gather loop 4 instr/neighbor
__global__ void __launch_bounds__(256)
k_attn1(const int* __restrict__ deg, const int* __restrict__ csr,
        const float* __restrict__ s1, const float* __restrict__ s2,
        const float* __restrict__ H, const float* __restrict__ bh,
        const float* __restrict__ cm1, float* __restrict__ X) {
    __shared__ float2 wts[4][CAP];
    int wid = threadIdx.x >> 6, lane = threadIdx.x & 63;
    int idx = blockIdx.x * 4 + wid;
    int n = idx & (NN - 1), h = idx >> 12;
    int d = deg[n]; d = min(d, CAP);
    float out;
    if (d == 0) {
        out = cm1[h * NHID + lane] * (1.0f / NN);
    } else {
        float s1n = s1[idx];
        const float* s2h = s2 + ((size_t)h << 12);
        const int* row = csr + (size_t)n * CAP;
        int t0 = (lane < d)       ? (row[lane]       & (NN - 1)) : 0;
        int t1 = (lane + 64 < d)  ? (row[lane + 64]  & (NN - 1)) : 0;
        int t2 = (lane + 128 < d) ? (row[lane + 128] & (NN - 1)) : 0;
        float e0 = (lane < d)       ? lrelu(s1n + s2h[t0]) : -1e30f;
        float e1 = (lane + 64 < d)  ? lrelu(s1n + s2h[t1]) : -1e30f;
        float e2 = (lane + 128 < d) ? lrelu(s1n + s2h[t2]) : -1e30f;
        float m = waveMax(fmaxf(e0, fmaxf(e1, e2)));
        float w0 = (lane < d)       ? __expf(e0 - m) : 0.f;
        float w1 = (lane + 64 < d)  ? __expf(e1 - m) : 0.f;
        float w2 = (lane + 128 < d) ? __expf(e2 - m) : 0.f;
        float den = waveSum(w0 + w1 + w2);
        wts[wid][lane]       = make_float2(w0, __int_as_float(t0 << 6));
        wts[wid][lane + 64]  = make_float2(w1, __int_as_float(t1 << 6));
        wts[wid][lane + 128] = make_float2(w2, __int_as_float(t2 << 6));
        const float* Hh = H + (((size_t)h << 12) * NHID);
        float acc = 0.f;
#pragma unroll 4
        for (int j = 0; j < d; ++j) {
            float2 p = wts[wid][j];
            acc += p.x * Hh[__float_as_int(p.y) + lane];
        }
        out = acc / den;
    }
    out += bh[h * NHID + lane];
    out = out > 0.f ? out : __expf(out) - 1.f;     // ELU
    X[(size_t)n * NFEAT + h * NHID + lane] = out;
}

// ---------- gemm2 + fused scores2 + colmean2 ----------
// wave per node: lane = (c, ksub); 128-iter K loop, coalesced Wo loads
__global__ void __launch_bounds__(256)
k_gemm2f(const float* __restrict__ X, const float* __restrict__ Wo,
         const float* __restrict__ ao, float* __restrict__ out2,
         float* __restrict__ s1o, float* __restrict__ s2o,
         float* __restrict__ cm2) {
    __shared__ float cms[16];
    int t = threadIdx.x;
    if (t < 16) cms[t] = 0.f;
    __syncthreads();
    int wid = t >> 6, lane = t & 63;
    int n = blockIdx.x * 4 + wid;
    int c = lane & 15, sub = lane >> 4;
    const float* xr = X + (size_t)n * NFEAT + sub * 128;
    const float* wr = Wo + sub * 128 * NCLASS + c;
    float acc = 0.f;
#pragma unroll 8
    for (int kk = 0; kk < 128; ++kk) acc += xr[kk] * wr[kk * NCLASS];
    acc += __shfl_xor(acc, 16, 64);
    acc += __shfl_xor(acc, 32, 64);
    if (lane < 16) out2[n * NCLASS + c] = acc;
    float r1 = acc * ao[c], r2 = acc * ao[NCLASS + c];
#pragma unroll
    for (int m = 8; m >= 1; m >>= 1) {
        r1 += __shfl_xor(r1, m, 16);
        r2 += __shfl_xor(r2, m, 16);
    }
    if (lane == 0) { s1o[n] = r1; s2o[n] = r2; }
    if (lane < 16) atomicAdd(&cms[c], acc);
    __syncthreads();
    if (t < 16) atomicAdd(&cm2[t], cms[t]);
}

// ---------- layer-2: softmax + SpMM + bias + log_softmax ----------
__global__ void __launch_bounds__(256)
k_attn2(const int* __restrict__ deg, const int* __restrict__ csr,
        const float* __restrict__ s1o, const float* __restrict__ s2o,
        const float* __restrict__ out2, const float* __restrict__ bo,
        const float* __restrict__ cm2, float* __restrict__ outp) {
    __shared__ float2 wts[4][CAP];
    int wid = threadIdx.x >> 6, lane = threadIdx.x & 63;
    int n = blockIdx.x * 4 + wid;
    int c = lane & 15, sub = lane >> 4;
    int d = deg[n]; d = min(d, CAP);
    float val;
    if (d == 0) {
        val = cm2[c] * (1.0f / NN);
    } else {
        float s1n = s1o[n];
        const int* row = csr + (size_t)n * CAP;
        int t0 = (lane < d)       ? (row[lane]       & (NN - 1)) : 0;
        int t1 = (lane + 64 < d)  ? (row[lane + 64]  & (NN - 1)) : 0;
        int t2 = (lane + 128 < d) ? (row[lane + 128] & (NN - 1)) : 0;
        float e0 = (lane < d)       ? lrelu(s1n + s2o[t0]) : -1e30f;
        float e1 = (lane + 64 < d)  ? lrelu(s1n + s2o[t1]) : -1e30f;
        float e2 = (lane + 128 < d) ? lrelu(s1n + s2o[t2]) : -1e30f;
        float m = waveMax(fmaxf(e0, fmaxf(e1, e2)));
        float w0 = (lane < d)       ? __expf(e0 - m) : 0.f;
        float w1 = (lane + 64 < d)  ? __expf(e1 - m) : 0.f;
        float w2 = (lane + 128 < d) ? __expf(e2 - m) : 0.f;
        float den = waveSum(w0 + w1 + w2);
        wts[wid][lane]       = make_float2(w0, __int_as_float(t0 << 4));
        wts[wid][lane + 64]  = make_float2(w1, __int_as_float(t1 << 4));
        wts[wid][lane + 128] = make_float2(w2, __int_as_float(t2 << 4));
        float acc = 0.f;
        for (int j = sub; j < d; j += 4) {
            float2 p = wts[wid][j];
            acc += p.x * out2[__float_as_int(p.y) + c];
        }
        acc += __shfl_xor(acc, 16, 64);
        acc += __shfl_xor(acc, 32, 64);
        val = acc / den;
    }
    val += bo[c];
    float mx = val;
#pragma unroll
    for (int m = 8; m >= 1; m >>= 1) mx = fmaxf(mx, __shfl_xor(mx, m, 16));
    float se = __expf(val - mx);
#pragma unroll
    for (int m = 8; m >= 1; m >>= 1) se += __shfl_xor(se, m, 16);
    float res = val - mx - __logf(se);
    if (lane < 16) outp[n * NCLASS + lane] = res;
}

extern "C" void kernel_launch(void* const* d_in, const int* in_sizes, int n_in,
                              void* d_out, int out_size, void* d_ws, size_t ws_size,
                              hipStream_t stream) {
    const void* features = d_in[0];
    const int*  edges    = (const int*)d_in[1];
    const void* W_heads  = d_in[2];
    const void* a_heads  = d_in[3];
    const void* b_heads  = d_in[4];
    const void* W_out    = d_in[5];
    const void* a_out    = d_in[6];
    const void* b_out    = d_in[7];
    int E = in_sizes[1] / 2;

    // ---- workspace layout (4B units) ----
    unsigned int* bits = (unsigned int*)d_ws;                  // NN*NN/32
    int*   deg  = (int*)(bits + (NN * NN / 32));               // NN
    float* cm1  = (float*)(deg + NN);                          // NHEAD*NHID
    float* cm2  = cm1 + NHEAD * NHID;                          // NCLASS
    int*   csr  = (int*)(cm2 + NCLASS);                        // NN*CAP
    float* H1   = (float*)(csr + NN * CAP);                    // NHEAD*NN*NHID
    float* s1   = H1 + (size_t)NHEAD * NN * NHID;              // NHEAD*NN
    float* s2   = s1 + NHEAD * NN;                             // NHEAD*NN
    float* X    = s2 + NHEAD * NN;                             // NN*NFEAT
    float* out2 = X + (size_t)NN * NFEAT;                      // NN*NCLASS
    float* s1o  = out2 + NN * NCLASS;                          // NN
    float* s2o  = s1o + NN;                                    // NN
    // contiguous fp32 copies of the float inputs (order matters for k_convert_all)
    float* featf = s2o + NN;                                   // SZ0
    float* Whf   = featf + SZ0;                                // SZ1
    float* ahf   = Whf + SZ1;                                  // SZ2
    float* bhf   = ahf + SZ2;                                  // SZ3
    float* Wof   = bhf + SZ3;                                  // SZ4
    float* aof   = Wof + SZ4;                                  // SZ5
    float* bof   = aof + SZ5;                                  // SZ6
    float* outp  = (float*)d_out;

    int zcount = NN * NN / 32 + NN + NHEAD * NHID + NCLASS;    // bits..cm2 contiguous
    hipLaunchKernelGGL(k_zero, dim3(1024), dim3(256), 0, stream, bits, zcount);
    hipLaunchKernelGGL(k_convert_all, dim3(2048), dim3(256), 0, stream,
                       features, W_heads, a_heads, b_heads, W_out, a_out, b_out, featf);
    hipLaunchKernelGGL(k_build_csr, dim3((E + 255) / 256), dim3(256), 0, stream,
                       edges, E, bits, deg, csr);
    hipLaunchKernelGGL(k_gemm1f, dim3(NN / 64, NHEAD), dim3(256), 0, stream,
                       featf, Whf, ahf, H1, s1, s2, cm1);
    hipLaunchKernelGGL(k_attn1, dim3(NN * NHEAD / 4), dim3(256), 0, stream,
                       deg, csr, s1, s2, H1, bhf, cm1, X);
    hipLaunchKernelGGL(k_gemm2f, dim3(NN / 4), dim3(256), 0, stream,
                       X, Wof, aof, out2, s1o, s2o, cm2);
    hipLaunchKernelGGL(k_attn2, dim3(NN / 4), dim3(256), 0, stream,
                       deg, csr, s1o, s2o, out2, bof, cm2, outp);
}

// Round 5
// 194.907 us; speedup vs baseline: 1.8130x; 1.1016x over previous
//
#include <hip/hip_runtime.h>
#include <hip/hip_bf16.h>

#define NN 4096
#define NFEAT 512
#define NHID 64
#define NHEAD 8
#define NCLASS 16
#define CAP 192
#define LALPHA 0.2f

#define SZ2 (NHEAD*2*NHID)   // a_heads
#define SZ3 (NHEAD*NHID)     // b_heads
#define SZ4 (NFEAT*NCLASS)   // W_out
#define SZ5 (2*NCLASS)       // a_out
#define SZ6 (NCLASS)         // b_out

typedef __attribute__((ext_vector_type(8))) short bf16x8;
typedef __attribute__((ext_vector_type(4))) float f32x4;

// ---------- helpers ----------
__device__ __forceinline__ float b2f(unsigned short h) {
    return __uint_as_float(((unsigned int)h) << 16);
}
__device__ __forceinline__ unsigned short f2b(float f) {
    unsigned int u = __float_as_uint(f);
    unsigned int r = (u + 0x7fffu + ((u >> 16) & 1u)) >> 16;
    return (unsigned short)r;
}
__device__ __forceinline__ float waveMax(float v) {
#pragma unroll
    for (int m = 32; m >= 1; m >>= 1) v = fmaxf(v, __shfl_xor(v, m, 64));
    return v;
}
__device__ __forceinline__ float waveSum(float v) {
#pragma unroll
    for (int m = 32; m >= 1; m >>= 1) v += __shfl_xor(v, m, 64);
    return v;
}
__device__ __forceinline__ float lrelu(float e) {
    return e >= 0.f ? e : LALPHA * e;
}

// ---------- zero bits+deg+cm1+cm2 ----------
__global__ void k_zero(unsigned int* __restrict__ p, int n) {
    int i = blockIdx.x * blockDim.x + threadIdx.x;
    int stride = gridDim.x * blockDim.x;
    for (; i < n; i += stride) p[i] = 0u;
}

// ---------- cast inputs: features->bf16, W_heads->bf16 transposed, small params->fp32 ----------
__global__ void k_cast(const void* __restrict__ f, const void* __restrict__ Wh_,
                       const void* __restrict__ ah_, const void* __restrict__ bh_,
                       const void* __restrict__ Wo_, const void* __restrict__ ao_,
                       const void* __restrict__ bo_,
                       unsigned short* __restrict__ featb,
                       unsigned short* __restrict__ Wtb,
                       float* __restrict__ smallf) {
    __shared__ int sbf;
    int t = threadIdx.x;
    if (t < 64) {
        unsigned int w = ((const unsigned int*)f)[t];
        unsigned int lo = w & 0xffffu, e = (lo >> 7) & 0xffu;
        unsigned long long bal = __ballot(lo == 0u || (e >= 100u && e <= 140u));
        if (t == 0) sbf = (__popcll(bal) >= 40);
    }
    __syncthreads();
    bool bf = (sbf != 0);
    const int T0 = NN * NFEAT;                      // featb
    const int T1 = T0 + NHEAD * NHID * NFEAT;       // Wtb (transposed)
    const int T2 = T1 + SZ2 + SZ3 + SZ4 + SZ5 + SZ6;
    int i = blockIdx.x * blockDim.x + t;
    int stride = gridDim.x * blockDim.x;
    for (; i < T2; i += stride) {
        if (i < T0) {
            featb[i] = bf ? ((const unsigned short*)f)[i] : f2b(((const float*)f)[i]);
        } else if (i < T1) {
            int r = i - T0;
            int h = r >> 15, rem = r & 32767;
            int n = rem >> 9, k = rem & 511;
            int si = (h << 15) + k * NHID + n;      // W[h][k][n]
            Wtb[r] = bf ? ((const unsigned short*)Wh_)[si] : f2b(((const float*)Wh_)[si]);
        } else {
            int r = i - T1;
            const void* sp; int off;
            if (r < SZ2)                       { sp = ah_; off = r; }
            else if (r < SZ2 + SZ3)            { sp = bh_; off = r - SZ2; }
            else if (r < SZ2 + SZ3 + SZ4)      { sp = Wo_; off = r - SZ2 - SZ3; }
            else if (r < SZ2 + SZ3 + SZ4 + SZ5){ sp = ao_; off = r - SZ2 - SZ3 - SZ4; }
            else                               { sp = bo_; off = r - SZ2 - SZ3 - SZ4 - SZ5; }
            smallf[r] = bf ? b2f(((const unsigned short*)sp)[off]) : ((const float*)sp)[off];
        }
    }
}

// ---------- dedup edges, build padded CSR (inline int64 detection) ----------
__global__ void k_build_csr(const int* __restrict__ e32, int E,
                            unsigned int* __restrict__ bits,
                            int* __restrict__ deg, int* __restrict__ csr) {
    __shared__ int s64f;
    int t = threadIdx.x;
    if (t < 64) {
        unsigned long long bal = __ballot(e32[2 * t + 1] == 0);
        if (t == 0) s64f = (__popcll(bal) >= 48);
    }
    __syncthreads();
    int i = blockIdx.x * blockDim.x + t;
    if (i >= E) return;
    int s, tt;
    if (s64f) { s = e32[2 * i]; tt = e32[2 * (E + i)]; }
    else      { s = e32[i];     tt = e32[E + i]; }
    s &= (NN - 1); tt &= (NN - 1);
    unsigned int pos = (unsigned int)s * NN + (unsigned int)tt;
    unsigned int mask = 1u << (pos & 31u);
    unsigned int old = atomicOr(&bits[pos >> 5], mask);
    if (!(old & mask)) {
        int j = atomicAdd(&deg[s], 1);
        if (j < CAP) csr[s * CAP + j] = tt;
    }
}

// ---------- MFMA gemm1 + fused scores1 + colmean1 ----------
// grid (32, 8), block 256 (4 waves). Wave computes 32 rows x 64 cols.
// A-frag: lane holds A[m0 + (lane&15)][k0 + (lane>>4)*8 + j]; B from W^T identically.
// C/D: col = lane&15 (+16*nt), row = (lane>>4)*4 + reg.
__global__ void __launch_bounds__(256)
k_gemm1m(const unsigned short* __restrict__ Ab,   // [NN][NFEAT] bf16
         const unsigned short* __restrict__ Wtb,  // [NHEAD][NHID][NFEAT] bf16 (transposed)
         const float* __restrict__ ah,            // [NHEAD][2*NHID]
         float* __restrict__ H,                   // [NHEAD][NN][NHID] fp32
         float* __restrict__ s1, float* __restrict__ s2,
         float* __restrict__ cm1) {
    __shared__ float cms[64];
    int t = threadIdx.x;
    if (t < 64) cms[t] = 0.f;
    __syncthreads();
    int w = t >> 6, l = t & 63;
    int quad = l >> 4, l16 = l & 15;
    int h = blockIdx.y;
    int m0 = blockIdx.x * 128 + w * 32;
    f32x4 acc[2][4] = {};
    const unsigned short* a0p = Ab + (size_t)(m0 + l16) * NFEAT + quad * 8;
    const unsigned short* a1p = a0p + 16 * NFEAT;
    const unsigned short* bp  = Wtb + ((size_t)h << 15) + (size_t)l16 * NFEAT + quad * 8;
#pragma unroll 4
    for (int k0 = 0; k0 < NFEAT; k0 += 32) {
        bf16x8 a0 = *(const bf16x8*)(a0p + k0);
        bf16x8 a1 = *(const bf16x8*)(a1p + k0);
#pragma unroll
        for (int nt = 0; nt < 4; ++nt) {
            bf16x8 b = *(const bf16x8*)(bp + (size_t)nt * 16 * NFEAT + k0);
            acc[0][nt] = __builtin_amdgcn_mfma_f32_16x16x32_bf16(a0, b, acc[0][nt], 0, 0, 0);
            acc[1][nt] = __builtin_amdgcn_mfma_f32_16x16x32_bf16(a1, b, acc[1][nt], 0, 0, 0);
        }
    }
    // epilogue: write H, fused s1/s2 row-dots, fused column sums
    const float* av = ah + h * 2 * NHID;
    float p1[2][4] = {}, p2[2][4] = {};
#pragma unroll
    for (int rh = 0; rh < 2; ++rh) {
#pragma unroll
        for (int nt = 0; nt < 4; ++nt) {
            int col = nt * 16 + l16;
            float av1 = av[col], av2 = av[NHID + col];
            float csum = 0.f;
#pragma unroll
            for (int r = 0; r < 4; ++r) {
                float v = acc[rh][nt][r];
                int row = m0 + rh * 16 + quad * 4 + r;
                H[(((size_t)h << 12) + row) * NHID + col] = v;
                p1[rh][r] += v * av1;
                p2[rh][r] += v * av2;
                csum += v;
            }
            atomicAdd(&cms[col], csum);
        }
    }
#pragma unroll
    for (int m = 8; m >= 1; m >>= 1)
#pragma unroll
        for (int rh = 0; rh < 2; ++rh)
#pragma unroll
            for (int r = 0; r < 4; ++r) {
                p1[rh][r] += __shfl_xor(p1[rh][r], m, 64);
                p2[rh][r] += __shfl_xor(p2[rh][r], m, 64);
            }
    if (l16 == 0) {
#pragma unroll
        for (int rh = 0; rh < 2; ++rh)
#pragma unroll
            for (int r = 0; r < 4; ++r) {
                int row = m0 + rh * 16 + quad * 4 + r;
                s1[(h << 12) + row] = p1[rh][r];
                s2[(h << 12) + row] = p2[rh][r];
            }
    }
    __syncthreads();
    if (t < 64) atomicAdd(&cm1[h * NHID + t], cms[t]);
}

// ---------- layer-1: softmax + SpMM + bias + ELU + concat ----------
// wave per (n,h). Weights precomputed to LDS; gather: 16-lane group per neighbor, float4/lane.
__global__ void __launch_bounds__(256)
k_attn1(const int* __restrict__ deg, const int* __restrict__ csr,
        const float* __restrict__ s1, const float* __restrict__ s2,
        const float* __restrict__ H, const float* __restrict__ bh,
        const float* __restrict__ cm1, float* __restrict__ X) {
    __shared__ float2 wts[4][CAP];
    int wid = threadIdx.x >> 6, lane = threadIdx.x & 63;
    int idx = blockIdx.x * 4 + wid;
    int n = idx & (NN - 1), h = idx >> 12;
    int l16 = lane & 15, sub = lane >> 4;
    int d = min(deg[n], CAP);
    float rx, ry, rz, rw;
    if (d == 0) {
        const float* c = cm1 + h * NHID + l16 * 4;
        rx = c[0] * (1.0f / NN); ry = c[1] * (1.0f / NN);
        rz = c[2] * (1.0f / NN); rw = c[3] * (1.0f / NN);
    } else {
        float s1n = s1[idx];
        const float* s2h = s2 + ((size_t)h << 12);
        const int* row = csr + (size_t)n * CAP;
        int t0 = (lane < d)       ? (row[lane]       & (NN - 1)) : 0;
        int t1 = (lane + 64 < d)  ? (row[lane + 64]  & (NN - 1)) : 0;
        int t2 = (lane + 128 < d) ? (row[lane + 128] & (NN - 1)) : 0;
        float e0 = (lane < d)       ? lrelu(s1n + s2h[t0]) : -1e30f;
        float e1 = (lane + 64 < d)  ? lrelu(s1n + s2h[t1]) : -1e30f;
        float e2 = (lane + 128 < d) ? lrelu(s1n + s2h[t2]) : -1e30f;
        float m = waveMax(fmaxf(e0, fmaxf(e1, e2)));
        float w0 = (lane < d)       ? __expf(e0 - m) : 0.f;
        float w1 = (lane + 64 < d)  ? __expf(e1 - m) : 0.f;
        float w2 = (lane + 128 < d) ? __expf(e2 - m) : 0.f;
        float den = waveSum(w0 + w1 + w2);
        wts[wid][lane]       = make_float2(w0, __int_as_float(t0 << 6));
        wts[wid][lane + 64]  = make_float2(w1, __int_as_float(t1 << 6));
        wts[wid][lane + 128] = make_float2(w2, __int_as_float(t2 << 6));
        const float* Hh = H + (((size_t)h << 12) * NHID);
        float ax = 0.f, ay = 0.f, az = 0.f, aw = 0.f;
#pragma unroll 2
        for (int j = sub; j < d; j += 4) {
            float2 p = wts[wid][j];
            const float* hp = Hh + __float_as_int(p.y) + l16 * 4;
            float4 v = *(const float4*)hp;
            ax += p.x * v.x; ay += p.x * v.y;
            az += p.x * v.z; aw += p.x * v.w;
        }
#pragma unroll
        for (int m2 = 32; m2 >= 16; m2 >>= 1) {
            ax += __shfl_xor(ax, m2, 64);
            ay += __shfl_xor(ay, m2, 64);
            az += __shfl_xor(az, m2, 64);
            aw += __shfl_xor(aw, m2, 64);
        }
        float rden = 1.0f / den;
        rx = ax * rden; ry = ay * rden; rz = az * rden; rw = aw * rden;
    }
    if (lane < 16) {
        const float* b4 = bh + h * NHID + l16 * 4;
        rx += b4[0]; ry += b4[1]; rz += b4[2]; rw += b4[3];
        rx = rx > 0.f ? rx : __expf(rx) - 1.f;
        ry = ry > 0.f ? ry : __expf(ry) - 1.f;
        rz = rz > 0.f ? rz : __expf(rz) - 1.f;
        rw = rw > 0.f ? rw : __expf(rw) - 1.f;
        float4 o = make_float4(rx, ry, rz, rw);
        *(float4*)&X[(size_t)n * NFEAT + h * NHID + l16 * 4] = o;
    }
}

// ---------- gemm2 + fused scores2 + colmean2 ----------
__global__ void __launch_bounds__(256)
k_gemm2f(const float* __restrict__ X, const float* __restrict__ Wo,
         const float* __restrict__ ao, float* __restrict__ out2,
         float* __restrict__ s1o, float* __restrict__ s2o,
         float* __restrict__ cm2) {
    __shared__ float cms[16];
    int t = threadIdx.x;
    if (t < 16) cms[t] = 0.f;
    __syncthreads();
    int wid = t >> 6, lane = t & 63;
    int n = blockIdx.x * 4 + wid;
    int c = lane & 15, sub = lane >> 4;
    const float* xr = X + (size_t)n * NFEAT + sub * 128;
    const float* wr = Wo + sub * 128 * NCLASS + c;
    float acc = 0.f;
#pragma unroll 8
    for (int kk = 0; kk < 128; ++kk) acc += xr[kk] * wr[kk * NCLASS];
    acc += __shfl_xor(acc, 16, 64);
    acc += __shfl_xor(acc, 32, 64);
    if (lane < 16) out2[n * NCLASS + c] = acc;
    float r1 = acc * ao[c], r2 = acc * ao[NCLASS + c];
#pragma unroll
    for (int m = 8; m >= 1; m >>= 1) {
        r1 += __shfl_xor(r1, m, 16);
        r2 += __shfl_xor(r2, m, 16);
    }
    if (lane == 0) { s1o[n] = r1; s2o[n] = r2; }
    if (lane < 16) atomicAdd(&cms[c], acc);
    __syncthreads();
    if (t < 16) atomicAdd(&cm2[t], cms[t]);
}

// ---------- layer-2: softmax + SpMM + bias + log_softmax ----------
__global__ void __launch_bounds__(256)
k_attn2(const int* __restrict__ deg, const int* __restrict__ csr,
        const float* __restrict__ s1o, const float* __restrict__ s2o,
        const float* __restrict__ out2, const float* __restrict__ bo,
        const float* __restrict__ cm2, float* __restrict__ outp) {
    __shared__ float2 wts[4][CAP];
    int wid = threadIdx.x >> 6, lane = threadIdx.x & 63;
    int n = blockIdx.x * 4 + wid;
    int c = lane & 15, sub = lane >> 4;
    int d = min(deg[n], CAP);
    float val;
    if (d == 0) {
        val = cm2[c] * (1.0f / NN);
    } else {
        float s1n = s1o[n];
        const int* row = csr + (size_t)n * CAP;
        int t0 = (lane < d)       ? (row[lane]       & (NN - 1)) : 0;
        int t1 = (lane + 64 < d)  ? (row[lane + 64]  & (NN - 1)) : 0;
        int t2 = (lane + 128 < d) ? (row[lane + 128] & (NN - 1)) : 0;
        float e0 = (lane < d)       ? lrelu(s1n + s2o[t0]) : -1e30f;
        float e1 = (lane + 64 < d)  ? lrelu(s1n + s2o[t1]) : -1e30f;
        float e2 = (lane + 128 < d) ? lrelu(s1n + s2o[t2]) : -1e30f;
        float m = waveMax(fmaxf(e0, fmaxf(e1, e2)));
        float w0 = (lane < d)       ? __expf(e0 - m) : 0.f;
        float w1 = (lane + 64 < d)  ? __expf(e1 - m) : 0.f;
        float w2 = (lane + 128 < d) ? __expf(e2 - m) : 0.f;
        float den = waveSum(w0 + w1 + w2);
        wts[wid][lane]       = make_float2(w0, __int_as_float(t0 << 4));
        wts[wid][lane + 64]  = make_float2(w1, __int_as_float(t1 << 4));
        wts[wid][lane + 128] = make_float2(w2, __int_as_float(t2 << 4));
        float acc = 0.f;
        for (int j = sub; j < d; j += 4) {
            float2 p = wts[wid][j];
            acc += p.x * out2[__float_as_int(p.y) + c];
        }
        acc += __shfl_xor(acc, 16, 64);
        acc += __shfl_xor(acc, 32, 64);
        val = acc / den;
    }
    val += bo[c];
    float mx = val;
#pragma unroll
    for (int m = 8; m >= 1; m >>= 1) mx = fmaxf(mx, __shfl_xor(mx, m, 16));
    float se = __expf(val - mx);
#pragma unroll
    for (int m = 8; m >= 1; m >>= 1) se += __shfl_xor(se, m, 16);
    float res = val - mx - __logf(se);
    if (lane < 16) outp[n * NCLASS + lane] = res;
}

extern "C" void kernel_launch(void* const* d_in, const int* in_sizes, int n_in,
                              void* d_out, int out_size, void* d_ws, size_t ws_size,
                              hipStream_t stream) {
    const void* features = d_in[0];
    const int*  edges    = (const int*)d_in[1];
    const void* W_heads  = d_in[2];
    const void* a_heads  = d_in[3];
    const void* b_heads  = d_in[4];
    const void* W_out    = d_in[5];
    const void* a_out    = d_in[6];
    const void* b_out    = d_in[7];
    int E = in_sizes[1] / 2;

    // ---- workspace layout (4B units) ----
    unsigned int* bits = (unsigned int*)d_ws;                  // NN*NN/32
    int*   deg  = (int*)(bits + (NN * NN / 32));               // NN
    float* cm1  = (float*)(deg + NN);                          // NHEAD*NHID
    float* cm2  = cm1 + NHEAD * NHID;                          // NCLASS
    int*   csr  = (int*)(cm2 + NCLASS);                        // NN*CAP
    float* H1   = (float*)(csr + NN * CAP);                    // NHEAD*NN*NHID
    float* s1   = H1 + (size_t)NHEAD * NN * NHID;              // NHEAD*NN
    float* s2   = s1 + NHEAD * NN;                             // NHEAD*NN
    float* X    = s2 + NHEAD * NN;                             // NN*NFEAT
    float* out2 = X + (size_t)NN * NFEAT;                      // NN*NCLASS
    float* s1o  = out2 + NN * NCLASS;                          // NN
    float* s2o  = s1o + NN;                                    // NN
    unsigned short* featb = (unsigned short*)(s2o + NN);       // NN*NFEAT bf16
    unsigned short* Wtb   = featb + (size_t)NN * NFEAT;        // NHEAD*NHID*NFEAT bf16
    float* smallf = (float*)(Wtb + NHEAD * NHID * NFEAT);      // small fp32 params
    float* ahf = smallf;
    float* bhf = ahf + SZ2;
    float* Wof = bhf + SZ3;
    float* aof = Wof + SZ4;
    float* bof = aof + SZ5;
    float* outp = (float*)d_out;

    int zcount = NN * NN / 32 + NN + NHEAD * NHID + NCLASS;    // bits..cm2 contiguous
    hipLaunchKernelGGL(k_zero, dim3(1024), dim3(256), 0, stream, bits, zcount);
    hipLaunchKernelGGL(k_cast, dim3(2048), dim3(256), 0, stream,
                       features, W_heads, a_heads, b_heads, W_out, a_out, b_out,
                       featb, Wtb, smallf);
    hipLaunchKernelGGL(k_build_csr, dim3((E + 255) / 256), dim3(256), 0, stream,
                       edges, E, bits, deg, csr);
    hipLaunchKernelGGL(k_gemm1m, dim3(32, NHEAD), dim3(256), 0, stream,
                       featb, Wtb, ahf, H1, s1, s2, cm1);
    hipLaunchKernelGGL(k_attn1, dim3(NN * NHEAD / 4), dim3(256), 0, stream,
                       deg, csr, s1, s2, H1, bhf, cm1, X);
    hipLaunchKernelGGL(k_gemm2f, dim3(NN / 4), dim3(256), 0, stream,
                       X, Wof, aof, out2, s1o, s2o, cm2);
    hipLaunchKernelGGL(k_attn2, dim3(NN / 4), dim3(256), 0, stream,
                       deg, csr, s1o, s2o, out2, bof, cm2, outp);
}

// Round 6
// 184.662 us; speedup vs baseline: 1.9136x; 1.0555x over previous
//
#include <hip/hip_runtime.h>
#include <hip/hip_bf16.h>

#define NN 4096
#define NFEAT 512
#define NHID 64
#define NHEAD 8
#define NCLASS 16
#define CAP 192
#define LALPHA 0.2f

#define SZ2 (NHEAD*2*NHID)   // a_heads
#define SZ3 (NHEAD*NHID)     // b_heads
#define SZ4 (NFEAT*NCLASS)   // W_out
#define SZ5 (2*NCLASS)       // a_out
#define SZ6 (NCLASS)         // b_out
#define NSMALL (SZ2+SZ3+SZ4+SZ5+SZ6)
#define NZERO (NN*NN/32 + NN + NHEAD*NHID + NCLASS)

typedef __attribute__((ext_vector_type(8))) short bf16x8;
typedef __attribute__((ext_vector_type(4))) float f32x4;
typedef __attribute__((ext_vector_type(4))) unsigned short u16x4;
typedef __attribute__((ext_vector_type(8))) unsigned short u16x8;

// ---------- helpers ----------
__device__ __forceinline__ float b2f(unsigned short h) {
    return __uint_as_float(((unsigned int)h) << 16);
}
__device__ __forceinline__ unsigned short f2b(float f) {
    unsigned int u = __float_as_uint(f);
    unsigned int r = (u + 0x7fffu + ((u >> 16) & 1u)) >> 16;
    return (unsigned short)r;
}
__device__ __forceinline__ float waveMax(float v) {
#pragma unroll
    for (int m = 32; m >= 1; m >>= 1) v = fmaxf(v, __shfl_xor(v, m, 64));
    return v;
}
__device__ __forceinline__ float waveSum(float v) {
#pragma unroll
    for (int m = 32; m >= 1; m >>= 1) v += __shfl_xor(v, m, 64);
    return v;
}
__device__ __forceinline__ float lrelu(float e) {
    return e >= 0.f ? e : LALPHA * e;
}

// ---------- prep: W-transpose tiles + zero + feature cast + small-param cast ----------
// blocks 0..127: transpose W_heads[h][k][n] -> Wtb[h][n][k] (bf16), LDS-tiled.
// blocks 128..: grid-stride over { zero words, features->bf16, smalls->fp32 }.
__global__ void __launch_bounds__(256)
k_prep(const void* __restrict__ f, const void* __restrict__ Wh_,
       const void* __restrict__ ah_, const void* __restrict__ bh_,
       const void* __restrict__ Wo_, const void* __restrict__ ao_,
       const void* __restrict__ bo_,
       unsigned short* __restrict__ featb,
       unsigned short* __restrict__ Wtb,
       float* __restrict__ smallf,
       unsigned int* __restrict__ zbase) {
    __shared__ int sbf;
    int t = threadIdx.x;
    if (t < 64) {
        unsigned int w = ((const unsigned int*)f)[t];
        unsigned int lo = w & 0xffffu, e = (lo >> 7) & 0xffu;
        unsigned long long bal = __ballot(lo == 0u || (e >= 100u && e <= 140u));
        if (t == 0) sbf = (__popcll(bal) >= 40);
    }
    __syncthreads();
    bool bf = (sbf != 0);
    if (blockIdx.x < 128) {
        // ---- transpose tile: h, 32 k x 64 n ----
        __shared__ float tile[64][33];
        int h = blockIdx.x >> 4, k0 = (blockIdx.x & 15) * 32;
        int n = t & 63, kh = t >> 6;                  // 4 k-groups of 8
#pragma unroll
        for (int i = 0; i < 8; ++i) {
            int kk = kh * 8 + i;
            int si = (h << 15) + (k0 + kk) * NHID + n;   // W[h][k][n]
            float v = bf ? b2f(((const unsigned short*)Wh_)[si])
                         : ((const float*)Wh_)[si];
            tile[n][kk] = v;
        }
        __syncthreads();
        int n2 = t >> 2, kk0 = (t & 3) * 8;
        u16x8 o;
#pragma unroll
        for (int i = 0; i < 8; ++i) o[i] = f2b(tile[n2][kk0 + i]);
        *(u16x8*)&Wtb[(size_t)((h << 6) + n2) * NFEAT + k0 + kk0] = o;
    } else {
        const int NF = NN * NFEAT;
        int i = (blockIdx.x - 128) * 256 + t;
        int stride = (gridDim.x - 128) * 256;
        const int TOT = NZERO + NF + NSMALL;
        for (; i < TOT; i += stride) {
            if (i < NZERO) {
                zbase[i] = 0u;
            } else if (i < NZERO + NF) {
                int r = i - NZERO;
                featb[r] = bf ? ((const unsigned short*)f)[r]
                              : f2b(((const float*)f)[r]);
            } else {
                int r = i - NZERO - NF;
                const void* sp; int off;
                if (r < SZ2)                        { sp = ah_; off = r; }
                else if (r < SZ2 + SZ3)             { sp = bh_; off = r - SZ2; }
                else if (r < SZ2 + SZ3 + SZ4)       { sp = Wo_; off = r - SZ2 - SZ3; }
                else if (r < SZ2 + SZ3 + SZ4 + SZ5) { sp = ao_; off = r - SZ2 - SZ3 - SZ4; }
                else                                { sp = bo_; off = r - SZ2 - SZ3 - SZ4 - SZ5; }
                smallf[r] = bf ? b2f(((const unsigned short*)sp)[off])
                               : ((const float*)sp)[off];
            }
        }
    }
}

// ---------- dedup edges, build padded CSR (inline int64 detection) ----------
__global__ void k_build_csr(const int* __restrict__ e32, int E,
                            unsigned int* __restrict__ bits,
                            int* __restrict__ deg, int* __restrict__ csr) {
    __shared__ int s64f;
    int t = threadIdx.x;
    if (t < 64) {
        unsigned long long bal = __ballot(e32[2 * t + 1] == 0);
        if (t == 0) s64f = (__popcll(bal) >= 48);
    }
    __syncthreads();
    int i = blockIdx.x * blockDim.x + t;
    if (i >= E) return;
    int s, tt;
    if (s64f) { s = e32[2 * i]; tt = e32[2 * (E + i)]; }
    else      { s = e32[i];     tt = e32[E + i]; }
    s &= (NN - 1); tt &= (NN - 1);
    unsigned int pos = (unsigned int)s * NN + (unsigned int)tt;
    unsigned int mask = 1u << (pos & 31u);
    unsigned int old = atomicOr(&bits[pos >> 5], mask);
    if (!(old & mask)) {
        int j = atomicAdd(&deg[s], 1);
        if (j < CAP) csr[s * CAP + j] = tt;
    }
}

// ---------- MFMA gemm1 + fused scores1 + colmean1; H stored bf16 ----------
__global__ void __launch_bounds__(256)
k_gemm1m(const unsigned short* __restrict__ Ab,   // [NN][NFEAT] bf16
         const unsigned short* __restrict__ Wtb,  // [NHEAD][NHID][NFEAT] bf16 (transposed)
         const float* __restrict__ ah,            // [NHEAD][2*NHID]
         unsigned short* __restrict__ Hb,         // [NHEAD][NN][NHID] bf16
         float* __restrict__ s1, float* __restrict__ s2,
         float* __restrict__ cm1) {
    __shared__ float cms[64];
    int t = threadIdx.x;
    if (t < 64) cms[t] = 0.f;
    __syncthreads();
    int w = t >> 6, l = t & 63;
    int quad = l >> 4, l16 = l & 15;
    int h = blockIdx.y;
    int m0 = blockIdx.x * 128 + w * 32;
    f32x4 acc[2][4] = {};
    const unsigned short* a0p = Ab + (size_t)(m0 + l16) * NFEAT + quad * 8;
    const unsigned short* a1p = a0p + 16 * NFEAT;
    const unsigned short* bp  = Wtb + ((size_t)h << 15) + (size_t)l16 * NFEAT + quad * 8;
#pragma unroll 4
    for (int k0 = 0; k0 < NFEAT; k0 += 32) {
        bf16x8 a0 = *(const bf16x8*)(a0p + k0);
        bf16x8 a1 = *(const bf16x8*)(a1p + k0);
#pragma unroll
        for (int nt = 0; nt < 4; ++nt) {
            bf16x8 b = *(const bf16x8*)(bp + (size_t)nt * 16 * NFEAT + k0);
            acc[0][nt] = __builtin_amdgcn_mfma_f32_16x16x32_bf16(a0, b, acc[0][nt], 0, 0, 0);
            acc[1][nt] = __builtin_amdgcn_mfma_f32_16x16x32_bf16(a1, b, acc[1][nt], 0, 0, 0);
        }
    }
    const float* av = ah + h * 2 * NHID;
    float p1[2][4] = {}, p2[2][4] = {};
#pragma unroll
    for (int rh = 0; rh < 2; ++rh) {
#pragma unroll
        for (int nt = 0; nt < 4; ++nt) {
            int col = nt * 16 + l16;
            float av1 = av[col], av2 = av[NHID + col];
            float csum = 0.f;
#pragma unroll
            for (int r = 0; r < 4; ++r) {
                float v = acc[rh][nt][r];
                int row = m0 + rh * 16 + quad * 4 + r;
                Hb[(((size_t)h << 12) + row) * NHID + col] = f2b(v);
                p1[rh][r] += v * av1;
                p2[rh][r] += v * av2;
                csum += v;
            }
            atomicAdd(&cms[col], csum);
        }
    }
#pragma unroll
    for (int m = 8; m >= 1; m >>= 1)
#pragma unroll
        for (int rh = 0; rh < 2; ++rh)
#pragma unroll
            for (int r = 0; r < 4; ++r) {
                p1[rh][r] += __shfl_xor(p1[rh][r], m, 64);
                p2[rh][r] += __shfl_xor(p2[rh][r], m, 64);
            }
    if (l16 == 0) {
#pragma unroll
        for (int rh = 0; rh < 2; ++rh)
#pragma unroll
            for (int r = 0; r < 4; ++r) {
                int row = m0 + rh * 16 + quad * 4 + r;
                s1[(h << 12) + row] = p1[rh][r];
                s2[(h << 12) + row] = p2[rh][r];
            }
    }
    __syncthreads();
    if (t < 64) atomicAdd(&cm1[h * NHID + t], cms[t]);
}

// ---------- layer-1: softmax + SpMM(bf16 H) + bias + ELU + concat ----------
__global__ void __launch_bounds__(256)
k_attn1(const int* __restrict__ deg, const int* __restrict__ csr,
        const float* __restrict__ s1, const float* __restrict__ s2,
        const unsigned short* __restrict__ Hb, const float* __restrict__ bh,
        const float* __restrict__ cm1, float* __restrict__ X) {
    __shared__ float2 wts[4][CAP];
    int wid = threadIdx.x >> 6, lane = threadIdx.x & 63;
    int idx = blockIdx.x * 4 + wid;
    int n = idx & (NN - 1), h = idx >> 12;
    int l16 = lane & 15, sub = lane >> 4;
    int d = min(deg[n], CAP);
    float rx, ry, rz, rw;
    if (d == 0) {
        const float* c = cm1 + h * NHID + l16 * 4;
        rx = c[0] * (1.0f / NN); ry = c[1] * (1.0f / NN);
        rz = c[2] * (1.0f / NN); rw = c[3] * (1.0f / NN);
    } else {
        float s1n = s1[idx];
        const float* s2h = s2 + ((size_t)h << 12);
        const int* row = csr + (size_t)n * CAP;
        int t0 = (lane < d)       ? (row[lane]       & (NN - 1)) : 0;
        int t1 = (lane + 64 < d)  ? (row[lane + 64]  & (NN - 1)) : 0;
        int t2 = (lane + 128 < d) ? (row[lane + 128] & (NN - 1)) : 0;
        float e0 = (lane < d)       ? lrelu(s1n + s2h[t0]) : -1e30f;
        float e1 = (lane + 64 < d)  ? lrelu(s1n + s2h[t1]) : -1e30f;
        float e2 = (lane + 128 < d) ? lrelu(s1n + s2h[t2]) : -1e30f;
        float m = waveMax(fmaxf(e0, fmaxf(e1, e2)));
        float w0 = (lane < d)       ? __expf(e0 - m) : 0.f;
        float w1 = (lane + 64 < d)  ? __expf(e1 - m) : 0.f;
        float w2 = (lane + 128 < d) ? __expf(e2 - m) : 0.f;
        float den = waveSum(w0 + w1 + w2);
        wts[wid][lane]       = make_float2(w0, __int_as_float(t0 << 6));
        wts[wid][lane + 64]  = make_float2(w1, __int_as_float(t1 << 6));
        wts[wid][lane + 128] = make_float2(w2, __int_as_float(t2 << 6));
        const unsigned short* Hh = Hb + (((size_t)h << 12) * NHID);
        float ax = 0.f, ay = 0.f, az = 0.f, aw = 0.f;
#pragma unroll 2
        for (int j = sub; j < d; j += 4) {
            float2 p = wts[wid][j];
            const unsigned short* hp = Hh + __float_as_int(p.y) + l16 * 4;
            u16x4 v = *(const u16x4*)hp;
            ax += p.x * b2f(v[0]); ay += p.x * b2f(v[1]);
            az += p.x * b2f(v[2]); aw += p.x * b2f(v[3]);
        }
#pragma unroll
        for (int m2 = 32; m2 >= 16; m2 >>= 1) {
            ax += __shfl_xor(ax, m2, 64);
            ay += __shfl_xor(ay, m2, 64);
            az += __shfl_xor(az, m2, 64);
            aw += __shfl_xor(aw, m2, 64);
        }
        float rden = 1.0f / den;
        rx = ax * rden; ry = ay * rden; rz = az * rden; rw = aw * rden;
    }
    if (lane < 16) {
        const float* b4 = bh + h * NHID + l16 * 4;
        rx += b4[0]; ry += b4[1]; rz += b4[2]; rw += b4[3];
        rx = rx > 0.f ? rx : __expf(rx) - 1.f;
        ry = ry > 0.f ? ry : __expf(ry) - 1.f;
        rz = rz > 0.f ? rz : __expf(rz) - 1.f;
        rw = rw > 0.f ? rw : __expf(rw) - 1.f;
        float4 o = make_float4(rx, ry, rz, rw);
        *(float4*)&X[(size_t)n * NFEAT + h * NHID + l16 * 4] = o;
    }
}

// ---------- gemm2 + fused scores2 + colmean2 ----------
__global__ void __launch_bounds__(256)
k_gemm2f(const float* __restrict__ X, const float* __restrict__ Wo,
         const float* __restrict__ ao, float* __restrict__ out2,
         float* __restrict__ s1o, float* __restrict__ s2o,
         float* __restrict__ cm2) {
    __shared__ float cms[16];
    int t = threadIdx.x;
    if (t < 16) cms[t] = 0.f;
    __syncthreads();
    int wid = t >> 6, lane = t & 63;
    int n = blockIdx.x * 4 + wid;
    int c = lane & 15, sub = lane >> 4;
    const float* xr = X + (size_t)n * NFEAT + sub * 128;
    const float* wr = Wo + sub * 128 * NCLASS + c;
    float acc = 0.f;
#pragma unroll 8
    for (int kk = 0; kk < 128; ++kk) acc += xr[kk] * wr[kk * NCLASS];
    acc += __shfl_xor(acc, 16, 64);
    acc += __shfl_xor(acc, 32, 64);
    if (lane < 16) out2[n * NCLASS + c] = acc;
    float r1 = acc * ao[c], r2 = acc * ao[NCLASS + c];
#pragma unroll
    for (int m = 8; m >= 1; m >>= 1) {
        r1 += __shfl_xor(r1, m, 16);
        r2 += __shfl_xor(r2, m, 16);
    }
    if (lane == 0) { s1o[n] = r1; s2o[n] = r2; }
    if (lane < 16) atomicAdd(&cms[c], acc);
    __syncthreads();
    if (t < 16) atomicAdd(&cm2[t], cms[t]);
}

// ---------- layer-2: softmax + SpMM + bias + log_softmax ----------
__global__ void __launch_bounds__(256)
k_attn2(const int* __restrict__ deg, const int* __restrict__ csr,
        const float* __restrict__ s1o, const float* __restrict__ s2o,
        const float* __restrict__ out2, const float* __restrict__ bo,
        const float* __restrict__ cm2, float* __restrict__ outp) {
    __shared__ float2 wts[4][CAP];
    int wid = threadIdx.x >> 6, lane = threadIdx.x & 63;
    int n = blockIdx.x * 4 + wid;
    int c = lane & 15, sub = lane >> 4;
    int d = min(deg[n], CAP);
    float val;
    if (d == 0) {
        val = cm2[c] * (1.0f / NN);
    } else {
        float s1n = s1o[n];
        const int* row = csr + (size_t)n * CAP;
        int t0 = (lane < d)       ? (row[lane]       & (NN - 1)) : 0;
        int t1 = (lane + 64 < d)  ? (row[lane + 64]  & (NN - 1)) : 0;
        int t2 = (lane + 128 < d) ? (row[lane + 128] & (NN - 1)) : 0;
        float e0 = (lane < d)       ? lrelu(s1n + s2o[t0]) : -1e30f;
        float e1 = (lane + 64 < d)  ? lrelu(s1n + s2o[t1]) : -1e30f;
        float e2 = (lane + 128 < d) ? lrelu(s1n + s2o[t2]) : -1e30f;
        float m = waveMax(fmaxf(e0, fmaxf(e1, e2)));
        float w0 = (lane < d)       ? __expf(e0 - m) : 0.f;
        float w1 = (lane + 64 < d)  ? __expf(e1 - m) : 0.f;
        float w2 = (lane + 128 < d) ? __expf(e2 - m) : 0.f;
        float den = waveSum(w0 + w1 + w2);
        wts[wid][lane]       = make_float2(w0, __int_as_float(t0 << 4));
        wts[wid][lane + 64]  = make_float2(w1, __int_as_float(t1 << 4));
        wts[wid][lane + 128] = make_float2(w2, __int_as_float(t2 << 4));
        float acc = 0.f;
        for (int j = sub; j < d; j += 4) {
            float2 p = wts[wid][j];
            acc += p.x * out2[__float_as_int(p.y) + c];
        }
        acc += __shfl_xor(acc, 16, 64);
        acc += __shfl_xor(acc, 32, 64);
        val = acc / den;
    }
    val += bo[c];
    float mx = val;
#pragma unroll
    for (int m = 8; m >= 1; m >>= 1) mx = fmaxf(mx, __shfl_xor(mx, m, 16));
    float se = __expf(val - mx);
#pragma unroll
    for (int m = 8; m >= 1; m >>= 1) se += __shfl_xor(se, m, 16);
    float res = val - mx - __logf(se);
    if (lane < 16) outp[n * NCLASS + lane] = res;
}

extern "C" void kernel_launch(void* const* d_in, const int* in_sizes, int n_in,
                              void* d_out, int out_size, void* d_ws, size_t ws_size,
                              hipStream_t stream) {
    const void* features = d_in[0];
    const int*  edges    = (const int*)d_in[1];
    const void* W_heads  = d_in[2];
    const void* a_heads  = d_in[3];
    const void* b_heads  = d_in[4];
    const void* W_out    = d_in[5];
    const void* a_out    = d_in[6];
    const void* b_out    = d_in[7];
    int E = in_sizes[1] / 2;

    // ---- workspace layout (4B units) ----
    unsigned int* bits = (unsigned int*)d_ws;                  // NN*NN/32
    int*   deg  = (int*)(bits + (NN * NN / 32));               // NN
    float* cm1  = (float*)(deg + NN);                          // NHEAD*NHID
    float* cm2  = cm1 + NHEAD * NHID;                          // NCLASS  (zero region ends)
    int*   csr  = (int*)(cm2 + NCLASS);                        // NN*CAP
    float* s1   = (float*)(csr + NN * CAP);                    // NHEAD*NN
    float* s2   = s1 + NHEAD * NN;                             // NHEAD*NN
    float* X    = s2 + NHEAD * NN;                             // NN*NFEAT
    float* out2 = X + (size_t)NN * NFEAT;                      // NN*NCLASS
    float* s1o  = out2 + NN * NCLASS;                          // NN
    float* s2o  = s1o + NN;                                    // NN
    unsigned short* Hb    = (unsigned short*)(s2o + NN);       // NHEAD*NN*NHID bf16
    unsigned short* featb = Hb + (size_t)NHEAD * NN * NHID;    // NN*NFEAT bf16
    unsigned short* Wtb   = featb + (size_t)NN * NFEAT;        // NHEAD*NHID*NFEAT bf16
    float* smallf = (float*)(Wtb + NHEAD * NHID * NFEAT);      // NSMALL fp32
    float* ahf = smallf;
    float* bhf = ahf + SZ2;
    float* Wof = bhf + SZ3;
    float* aof = Wof + SZ4;
    float* bof = aof + SZ5;
    float* outp = (float*)d_out;

    hipLaunchKernelGGL(k_prep, dim3(2048), dim3(256), 0, stream,
                       features, W_heads, a_heads, b_heads, W_out, a_out, b_out,
                       featb, Wtb, smallf, bits);
    hipLaunchKernelGGL(k_build_csr, dim3((E + 255) / 256), dim3(256), 0, stream,
                       edges, E, bits, deg, csr);
    hipLaunchKernelGGL(k_gemm1m, dim3(32, NHEAD), dim3(256), 0, stream,
                       featb, Wtb, ahf, Hb, s1, s2, cm1);
    hipLaunchKernelGGL(k_attn1, dim3(NN * NHEAD / 4), dim3(256), 0, stream,
                       deg, csr, s1, s2, Hb, bhf, cm1, X);
    hipLaunchKernelGGL(k_gemm2f, dim3(NN / 4), dim3(256), 0, stream,
                       X, Wof, aof, out2, s1o, s2o, cm2);
    hipLaunchKernelGGL(k_attn2, dim3(NN / 4), dim3(256), 0, stream,
                       deg, csr, s1o, s2o, out2, bof, cm2, outp);
}